// Round 1
// baseline (279.568 us; speedup 1.0000x reference)
//
#include <hip/hip_runtime.h>

#define B_ 8
#define L_ 4096
#define D_ 512
#define M_ 64
#define NC_ 32            // l-chunks for stage 1 (grid = NC_*B_ = 256 blocks)
#define LCH (L_ / NC_)    // 128
#define DCH 4             // d-chunks for stage 2

// ---------------------------------------------------------------- twiddle table
__global__ void k_tab(float2* __restrict__ tab) {
  int t = blockIdx.x * blockDim.x + threadIdx.x;
  if (t < L_) {
    double ang = 6.283185307179586476925286766559 * (double)t / (double)L_;
    tab[t] = make_float2((float)cos(ang), (float)sin(ang));
  }
}

// ------------------------------------------------- stage 1: truncated forward DFT
// grid (NC_, B_), block 512 = 8 waves. wave w owns k in [8w, 8w+8); lane owns 8 d.
// Qr[b,k,d] = sum_l q*cos(2pikl/L); Qi[b,k,d] = -sum_l q*sin(2pikl/L)
__global__ __launch_bounds__(512) void k_dft(
    const float* __restrict__ q, const float2* __restrict__ tab,
    float* __restrict__ pQr, float* __restrict__ pQi) {
  __shared__ float2 s_tab[L_];
  int tid = threadIdx.x;
#pragma unroll
  for (int i = 0; i < 8; ++i) s_tab[tid + i * 512] = tab[tid + i * 512];
  __syncthreads();

  int c = blockIdx.x, b = blockIdx.y;
  int w = tid >> 6, lane = tid & 63;
  int kb = w * 8;
  int db = lane * 8;

  float ar[8][8], ai[8][8];
#pragma unroll
  for (int kk = 0; kk < 8; ++kk) {
#pragma unroll
    for (int j = 0; j < 8; ++j) { ar[kk][j] = 0.f; ai[kk][j] = 0.f; }
  }

  int idx[8];
  int l0 = c * LCH;
#pragma unroll
  for (int kk = 0; kk < 8; ++kk) idx[kk] = ((kb + kk) * l0) & (L_ - 1);

  const float* qp = q + (((size_t)b * L_ + l0) * D_ + db);
#pragma unroll 2
  for (int l = 0; l < LCH; ++l) {
    float4 q0 = *(const float4*)qp;
    float4 q1 = *(const float4*)(qp + 4);
    qp += D_;
    float qv[8] = {q0.x, q0.y, q0.z, q0.w, q1.x, q1.y, q1.z, q1.w};
#pragma unroll
    for (int kk = 0; kk < 8; ++kk) {
      float2 t = s_tab[idx[kk]];
      idx[kk] = (idx[kk] + kb + kk) & (L_ - 1);
#pragma unroll
      for (int j = 0; j < 8; ++j) {
        ar[kk][j] += qv[j] * t.x;
        ai[kk][j] -= qv[j] * t.y;
      }
    }
  }

#pragma unroll
  for (int kk = 0; kk < 8; ++kk) {
    size_t base = (((size_t)b * NC_ + c) * M_ + (kb + kk)) * D_ + db;
    *(float4*)(pQr + base)     = make_float4(ar[kk][0], ar[kk][1], ar[kk][2], ar[kk][3]);
    *(float4*)(pQr + base + 4) = make_float4(ar[kk][4], ar[kk][5], ar[kk][6], ar[kk][7]);
    *(float4*)(pQi + base)     = make_float4(ai[kk][0], ai[kk][1], ai[kk][2], ai[kk][3]);
    *(float4*)(pQi + base + 4) = make_float4(ai[kk][4], ai[kk][5], ai[kk][6], ai[kk][7]);
  }
}

// ----------------------------------- reduce chunks + transpose to Qt[b][d][k] (float2)
__global__ void k_red(const float* __restrict__ pQr, const float* __restrict__ pQi,
                      float2* __restrict__ Qt) {
  int g = blockIdx.x * 256 + threadIdx.x;  // B_*M_*D_ threads
  int d = g & (D_ - 1);
  int k = (g >> 9) & (M_ - 1);
  int b = g >> 15;
  float ar = 0.f, ai = 0.f;
  for (int c = 0; c < NC_; ++c) {
    size_t base = (((size_t)b * NC_ + c) * M_ + k) * D_ + d;
    ar += pQr[base];
    ai += pQi[base];
  }
  Qt[((size_t)b * D_ + d) * M_ + k] = make_float2(ar, ai);
}

// ---------------------------------------------- stage 2: mode mixing (complex GEMM)
// grid (D_/8, DCH), block 512 = 8 waves. wave w -> e = 8*bx+w, lane -> k.
// O[b,k,e] = sum_d Qft[b,k,d] * W[d,e,k]
__global__ __launch_bounds__(512) void k_mix(
    const float* __restrict__ wr_, const float* __restrict__ wi_,
    const float2* __restrict__ Qt, float2* __restrict__ pO) {
  int tid = threadIdx.x;
  int w = tid >> 6, k = tid & 63;
  int e = blockIdx.x * 8 + w;
  int dc = blockIdx.y;
  float or_[B_], oi_[B_];
#pragma unroll
  for (int b = 0; b < B_; ++b) { or_[b] = 0.f; oi_[b] = 0.f; }
#pragma unroll 2
  for (int d = dc * 128; d < dc * 128 + 128; ++d) {
    float wr = wr_[((size_t)d * D_ + e) * M_ + k];
    float wi = wi_[((size_t)d * D_ + e) * M_ + k];
#pragma unroll
    for (int b = 0; b < B_; ++b) {
      float2 qv = Qt[((size_t)b * D_ + d) * M_ + k];
      or_[b] += qv.x * wr - qv.y * wi;
      oi_[b] += qv.x * wi + qv.y * wr;
    }
  }
#pragma unroll
  for (int b = 0; b < B_; ++b)
    pO[(((size_t)dc * B_ + b) * D_ + e) * M_ + k] = make_float2(or_[b], oi_[b]);
}

// ------------------------------------------------- stage 3: truncated inverse DFT
// grid (D_/32, L_/512, B_), block 256. Thread tile: 8 l x 8 e. Twiddle by recurrence.
#define EPB 32
#define PADK 33
__global__ __launch_bounds__(256) void k_inv(
    const float2* __restrict__ pO, const float2* __restrict__ tab,
    float* __restrict__ y) {
  __shared__ float2 sO[M_][PADK];  // [k][e within block], summed over DCH chunks
  int tid = threadIdx.x;
  int et = blockIdx.x, lt = blockIdx.y, b = blockIdx.z;
  int e0 = et * EPB;
  {
    int k = tid & 63;
    for (int e = tid >> 6; e < EPB; e += 4) {
      float2 acc = make_float2(0.f, 0.f);
#pragma unroll
      for (int c = 0; c < DCH; ++c) {
        float2 v = pO[(((size_t)c * B_ + b) * D_ + (e0 + e)) * M_ + k];
        acc.x += v.x; acc.y += v.y;
      }
      sO[k][e] = acc;
    }
  }
  __syncthreads();

  int lg = tid >> 2, eg = tid & 3;
  int lbase = lt * 512 + lg * 8;
  int esub = eg * 8;

  float acc[8][8];
#pragma unroll
  for (int li = 0; li < 8; ++li) {
#pragma unroll
    for (int j = 0; j < 8; ++j) acc[li][j] = 0.f;
  }

  // per-l step twiddle e^{+2pi i l/L}; running twiddle starts at k=1
  float wc[8], ws[8], sc[8], ss[8];
#pragma unroll
  for (int li = 0; li < 8; ++li) {
    float2 st = tab[lbase + li];
    sc[li] = st.x; ss[li] = st.y;
    wc[li] = st.x; ws[li] = st.y;
  }

  for (int k = 1; k < M_; ++k) {
    float orv[8], oiv[8];
#pragma unroll
    for (int j = 0; j < 8; ++j) {
      float2 v = sO[k][esub + j];
      orv[j] = v.x; oiv[j] = v.y;
    }
#pragma unroll
    for (int li = 0; li < 8; ++li) {
#pragma unroll
      for (int j = 0; j < 8; ++j)
        acc[li][j] += orv[j] * wc[li] - oiv[j] * ws[li];
    }
#pragma unroll
    for (int li = 0; li < 8; ++li) {
      float nc = wc[li] * sc[li] - ws[li] * ss[li];
      float ns = wc[li] * ss[li] + ws[li] * sc[li];
      wc[li] = nc; ws[li] = ns;
    }
  }

  const float inv = 1.0f / (float)L_;
#pragma unroll
  for (int li = 0; li < 8; ++li) {
    int l = lbase + li;
    float o[8];
#pragma unroll
    for (int j = 0; j < 8; ++j)
      o[j] = (sO[0][esub + j].x + 2.f * acc[li][j]) * inv;
    size_t base = ((size_t)b * L_ + l) * D_ + e0 + esub;
    *(float4*)(y + base)     = make_float4(o[0], o[1], o[2], o[3]);
    *(float4*)(y + base + 4) = make_float4(o[4], o[5], o[6], o[7]);
  }
}

// --------------------------------------------------------------------- launcher
extern "C" void kernel_launch(void* const* d_in, const int* in_sizes, int n_in,
                              void* d_out, int out_size, void* d_ws, size_t ws_size,
                              hipStream_t stream) {
  const float* q  = (const float*)d_in[0];
  const float* wr = (const float*)d_in[1];
  const float* wi = (const float*)d_in[2];
  float* out = (float*)d_out;
  char* ws = (char*)d_ws;

  // ws layout: tab 32KB | Qt 2MB | pO 8MB  (total ~10.03 MB)
  float2* tab = (float2*)ws;
  float2* Qt  = (float2*)(ws + (32u << 10));
  float2* pO  = (float2*)(ws + (32u << 10) + (2u << 20));

  // Stage-1 partials live in d_out (dead before k_inv writes it):
  // pQr = first 32MB, pQi = second 32MB. B_*NC_*M_*D_ floats each.
  float* pQr = out;
  float* pQi = out + (size_t)B_ * NC_ * M_ * D_;

  hipLaunchKernelGGL(k_tab, dim3(L_ / 256), dim3(256), 0, stream, tab);
  hipLaunchKernelGGL(k_dft, dim3(NC_, B_), dim3(512), 0, stream, q, tab, pQr, pQi);
  hipLaunchKernelGGL(k_red, dim3((B_ * M_ * D_) / 256), dim3(256), 0, stream,
                     pQr, pQi, Qt);
  hipLaunchKernelGGL(k_mix, dim3(D_ / 8, DCH), dim3(512), 0, stream, wr, wi, Qt, pO);
  hipLaunchKernelGGL(k_inv, dim3(D_ / EPB, L_ / 512, B_), dim3(256), 0, stream,
                     pO, tab, out);
}

// Round 2
// 244.301 us; speedup vs baseline: 1.1444x; 1.1444x over previous
//
#include <hip/hip_runtime.h>

#define B_ 8
#define L_ 4096
#define D_ 512
#define M_ 64
#define NC_ 32            // l-chunks for stage 1 (grid = NC_*B_ = 256 blocks)
#define LCH (L_ / NC_)    // 128

// ---------------------------------------------------------------- twiddle table
__global__ void k_tab(float2* __restrict__ tab) {
  int t = blockIdx.x * blockDim.x + threadIdx.x;
  if (t < L_) {
    double ang = 6.283185307179586476925286766559 * (double)t / (double)L_;
    tab[t] = make_float2((float)cos(ang), (float)sin(ang));
  }
}

// ------------------------------------------------- stage 1: truncated forward DFT
__global__ __launch_bounds__(512) void k_dft(
    const float* __restrict__ q, const float2* __restrict__ tab,
    float* __restrict__ pQr, float* __restrict__ pQi) {
  __shared__ float2 s_tab[L_];
  int tid = threadIdx.x;
#pragma unroll
  for (int i = 0; i < 8; ++i) s_tab[tid + i * 512] = tab[tid + i * 512];
  __syncthreads();

  int c = blockIdx.x, b = blockIdx.y;
  int w = tid >> 6, lane = tid & 63;
  int kb = w * 8;
  int db = lane * 8;

  float ar[8][8], ai[8][8];
#pragma unroll
  for (int kk = 0; kk < 8; ++kk) {
#pragma unroll
    for (int j = 0; j < 8; ++j) { ar[kk][j] = 0.f; ai[kk][j] = 0.f; }
  }

  int idx[8];
  int l0 = c * LCH;
#pragma unroll
  for (int kk = 0; kk < 8; ++kk) idx[kk] = ((kb + kk) * l0) & (L_ - 1);

  const float* qp = q + (((size_t)b * L_ + l0) * D_ + db);
#pragma unroll 2
  for (int l = 0; l < LCH; ++l) {
    float4 q0 = *(const float4*)qp;
    float4 q1 = *(const float4*)(qp + 4);
    qp += D_;
    float qv[8] = {q0.x, q0.y, q0.z, q0.w, q1.x, q1.y, q1.z, q1.w};
#pragma unroll
    for (int kk = 0; kk < 8; ++kk) {
      float2 t = s_tab[idx[kk]];
      idx[kk] = (idx[kk] + kb + kk) & (L_ - 1);
#pragma unroll
      for (int j = 0; j < 8; ++j) {
        ar[kk][j] += qv[j] * t.x;
        ai[kk][j] -= qv[j] * t.y;
      }
    }
  }

#pragma unroll
  for (int kk = 0; kk < 8; ++kk) {
    size_t base = (((size_t)b * NC_ + c) * M_ + (kb + kk)) * D_ + db;
    *(float4*)(pQr + base)     = make_float4(ar[kk][0], ar[kk][1], ar[kk][2], ar[kk][3]);
    *(float4*)(pQr + base + 4) = make_float4(ar[kk][4], ar[kk][5], ar[kk][6], ar[kk][7]);
    *(float4*)(pQi + base)     = make_float4(ai[kk][0], ai[kk][1], ai[kk][2], ai[kk][3]);
    *(float4*)(pQi + base + 4) = make_float4(ai[kk][4], ai[kk][5], ai[kk][6], ai[kk][7]);
  }
}

// ----------------------------------- reduce chunks + transpose to Qt[b][d][k] (float2)
__global__ void k_red(const float* __restrict__ pQr, const float* __restrict__ pQi,
                      float2* __restrict__ Qt) {
  int g = blockIdx.x * 256 + threadIdx.x;  // B_*M_*D_ threads
  int d = g & (D_ - 1);
  int k = (g >> 9) & (M_ - 1);
  int b = g >> 15;
  float ar = 0.f, ai = 0.f;
  for (int c = 0; c < NC_; ++c) {
    size_t base = (((size_t)b * NC_ + c) * M_ + k) * D_ + d;
    ar += pQr[base];
    ai += pQi[base];
  }
  Qt[((size_t)b * D_ + d) * M_ + k] = make_float2(ar, ai);
}

// ---------------------------------------------- stage 2: mode mixing (complex GEMM)
// grid (D_/4, DCH), block 256 = 4 waves. wave w -> e = 4*bx+w.
// lane = (kq, dd): kq = lane&15 -> k0 = 4*kq (float4 W loads); dd = lane>>4 -> 4 d/iter.
// Cross-lane reduce over dd at the end (shfl_xor 16, 32).
template <int DCH>
__global__ __launch_bounds__(256, 4) void k_mix(
    const float* __restrict__ wr_, const float* __restrict__ wi_,
    const float* __restrict__ Qt /* float2 as float */, float2* __restrict__ pO) {
  constexpr int DC = D_ / DCH;
  int tid = threadIdx.x;
  int w = tid >> 6, lane = tid & 63;
  int kq = lane & 15, dd = lane >> 4;
  int k0 = kq * 4;
  int e = blockIdx.x * 4 + w;
  int dc = blockIdx.y;

  float or_[B_][4], oi_[B_][4];
#pragma unroll
  for (int b = 0; b < B_; ++b)
#pragma unroll
    for (int kk = 0; kk < 4; ++kk) { or_[b][kk] = 0.f; oi_[b][kk] = 0.f; }

  int d0 = dc * DC + dd;
  const float* wrp = wr_ + ((size_t)d0 * D_ + e) * M_ + k0;
  const float* wip = wi_ + ((size_t)d0 * D_ + e) * M_ + k0;
  const float* qt0 = Qt + ((size_t)d0 * M_ + k0) * 2;

#pragma unroll 2
  for (int s = 0; s < DC; s += 4) {
    float4 wr4 = *(const float4*)wrp;
    float4 wi4 = *(const float4*)wip;
    wrp += (size_t)4 * D_ * M_;
    wip += (size_t)4 * D_ * M_;
    const float* qp = qt0;
#pragma unroll
    for (int b = 0; b < B_; ++b) {
      float4 qa = *(const float4*)qp;        // r0 i0 r1 i1
      float4 qb = *(const float4*)(qp + 4);  // r2 i2 r3 i3
      qp += (size_t)D_ * M_ * 2;
      or_[b][0] += qa.x * wr4.x - qa.y * wi4.x;
      oi_[b][0] += qa.x * wi4.x + qa.y * wr4.x;
      or_[b][1] += qa.z * wr4.y - qa.w * wi4.y;
      oi_[b][1] += qa.z * wi4.y + qa.w * wr4.y;
      or_[b][2] += qb.x * wr4.z - qb.y * wi4.z;
      oi_[b][2] += qb.x * wi4.z + qb.y * wr4.z;
      or_[b][3] += qb.z * wr4.w - qb.w * wi4.w;
      oi_[b][3] += qb.z * wi4.w + qb.w * wr4.w;
    }
    qt0 += 4 * M_ * 2;
  }

#pragma unroll
  for (int b = 0; b < B_; ++b)
#pragma unroll
    for (int kk = 0; kk < 4; ++kk) {
      or_[b][kk] += __shfl_xor(or_[b][kk], 16, 64);
      or_[b][kk] += __shfl_xor(or_[b][kk], 32, 64);
      oi_[b][kk] += __shfl_xor(oi_[b][kk], 16, 64);
      oi_[b][kk] += __shfl_xor(oi_[b][kk], 32, 64);
    }

  if (dd == 0) {
    float* base = (float*)pO;
#pragma unroll
    for (int b = 0; b < B_; ++b) {
      size_t off = ((((size_t)dc * B_ + b) * D_ + e) * M_ + k0) * 2;
      *(float4*)(base + off)     = make_float4(or_[b][0], oi_[b][0], or_[b][1], oi_[b][1]);
      *(float4*)(base + off + 4) = make_float4(or_[b][2], oi_[b][2], or_[b][3], oi_[b][3]);
    }
  }
}

// ------------------------------------------------- stage 3: truncated inverse DFT
#define EPB 32
#define PADK 33
template <int DCH>
__global__ __launch_bounds__(256) void k_inv(
    const float2* __restrict__ pO, const float2* __restrict__ tab,
    float* __restrict__ y) {
  __shared__ float2 sO[M_][PADK];
  int tid = threadIdx.x;
  int et = blockIdx.x, lt = blockIdx.y, b = blockIdx.z;
  int e0 = et * EPB;
  {
    int k = tid & 63;
    for (int e = tid >> 6; e < EPB; e += 4) {
      float2 acc = make_float2(0.f, 0.f);
#pragma unroll
      for (int c = 0; c < DCH; ++c) {
        float2 v = pO[(((size_t)c * B_ + b) * D_ + (e0 + e)) * M_ + k];
        acc.x += v.x; acc.y += v.y;
      }
      sO[k][e] = acc;
    }
  }
  __syncthreads();

  int lg = tid >> 2, eg = tid & 3;
  int lbase = lt * 512 + lg * 8;
  int esub = eg * 8;

  float acc[8][8];
#pragma unroll
  for (int li = 0; li < 8; ++li)
#pragma unroll
    for (int j = 0; j < 8; ++j) acc[li][j] = 0.f;

  float wc[8], ws[8], sc[8], ss[8];
#pragma unroll
  for (int li = 0; li < 8; ++li) {
    float2 st = tab[lbase + li];
    sc[li] = st.x; ss[li] = st.y;
    wc[li] = st.x; ws[li] = st.y;
  }

  for (int k = 1; k < M_; ++k) {
    float orv[8], oiv[8];
#pragma unroll
    for (int j = 0; j < 8; ++j) {
      float2 v = sO[k][esub + j];
      orv[j] = v.x; oiv[j] = v.y;
    }
#pragma unroll
    for (int li = 0; li < 8; ++li)
#pragma unroll
      for (int j = 0; j < 8; ++j)
        acc[li][j] += orv[j] * wc[li] - oiv[j] * ws[li];
#pragma unroll
    for (int li = 0; li < 8; ++li) {
      float nc = wc[li] * sc[li] - ws[li] * ss[li];
      float ns = wc[li] * ss[li] + ws[li] * sc[li];
      wc[li] = nc; ws[li] = ns;
    }
  }

  const float inv = 1.0f / (float)L_;
#pragma unroll
  for (int li = 0; li < 8; ++li) {
    int l = lbase + li;
    float o[8];
#pragma unroll
    for (int j = 0; j < 8; ++j)
      o[j] = (sO[0][esub + j].x + 2.f * acc[li][j]) * inv;
    size_t base = ((size_t)b * L_ + l) * D_ + e0 + esub;
    *(float4*)(y + base)     = make_float4(o[0], o[1], o[2], o[3]);
    *(float4*)(y + base + 4) = make_float4(o[4], o[5], o[6], o[7]);
  }
}

// --------------------------------------------------------------------- launcher
extern "C" void kernel_launch(void* const* d_in, const int* in_sizes, int n_in,
                              void* d_out, int out_size, void* d_ws, size_t ws_size,
                              hipStream_t stream) {
  const float* q  = (const float*)d_in[0];
  const float* wr = (const float*)d_in[1];
  const float* wi = (const float*)d_in[2];
  float* out = (float*)d_out;
  char* ws = (char*)d_ws;

  // ws layout: tab 32KB | Qt 2MB | pO (DCH*B*D*M float2)
  float2* tab = (float2*)ws;
  float2* Qt  = (float2*)(ws + (32u << 10));
  float2* pO  = (float2*)(ws + (32u << 10) + (2u << 20));

  float* pQr = out;
  float* pQi = out + (size_t)B_ * NC_ * M_ * D_;

  size_t head = (32u << 10) + (2u << 20);
  size_t po8 = (size_t)8 * B_ * D_ * M_ * sizeof(float2);  // 16.8 MB

  hipLaunchKernelGGL(k_tab, dim3(L_ / 256), dim3(256), 0, stream, tab);
  hipLaunchKernelGGL(k_dft, dim3(NC_, B_), dim3(512), 0, stream, q, tab, pQr, pQi);
  hipLaunchKernelGGL(k_red, dim3((B_ * M_ * D_) / 256), dim3(256), 0, stream,
                     pQr, pQi, Qt);

  if (ws_size >= head + po8) {
    hipLaunchKernelGGL((k_mix<8>), dim3(D_ / 4, 8), dim3(256), 0, stream,
                       wr, wi, (const float*)Qt, pO);
    hipLaunchKernelGGL((k_inv<8>), dim3(D_ / EPB, L_ / 512, B_), dim3(256), 0,
                       stream, pO, tab, out);
  } else {
    hipLaunchKernelGGL((k_mix<4>), dim3(D_ / 4, 4), dim3(256), 0, stream,
                       wr, wi, (const float*)Qt, pO);
    hipLaunchKernelGGL((k_inv<4>), dim3(D_ / EPB, L_ / 512, B_), dim3(256), 0,
                       stream, pO, tab, out);
  }
}

// Round 4
// 177.259 us; speedup vs baseline: 1.5772x; 1.3782x over previous
//
#include <hip/hip_runtime.h>

#define B_ 8
#define L_ 4096
#define D_ 512
#define M_ 64
#define NC_ 32            // l-chunks for stage 1
#define LCH (L_ / NC_)    // 128
#define DCH 8             // d-chunks for stage 2

typedef __attribute__((ext_vector_type(8))) short bh8;
typedef __attribute__((ext_vector_type(4))) float f4;

__device__ inline unsigned short f2bf(float f) {
  unsigned u = __float_as_uint(f);
  return (unsigned short)((u + 0x7fffu + ((u >> 16) & 1u)) >> 16);
}

// ---------------------------------------------------------------- twiddle table
__global__ void k_tab(float2* __restrict__ tab) {
  int t = blockIdx.x * blockDim.x + threadIdx.x;
  if (t < L_) {
    double ang = 6.283185307179586476925286766559 * (double)t / (double)L_;
    tab[t] = make_float2((float)cos(ang), (float)sin(ang));
  }
}

// ----------------------------------------- inverse-DFT coefficient matrix (bf16)
// G[l][2k]   = ck*cos(2pi k l / L),  G[l][2k+1] = -ck*sin(2pi k l / L)
// ck = 1/L for k=0 (imag of bin 0 ignored by irfft), 2/L otherwise.
__global__ void k_gtab(unsigned* __restrict__ G) {
  int t = blockIdx.x * 256 + threadIdx.x;  // L_*M_ = 262144
  int l = t >> 6, k = t & 63;
  int ph = (k * l) & (L_ - 1);
  double ang = 6.283185307179586476925286766559 * (double)ph / (double)L_;
  double ck = (k == 0 ? 1.0 : 2.0) / (double)L_;
  unsigned lo = f2bf((float)(ck * cos(ang)));
  unsigned hi = f2bf((float)(-ck * sin(ang)));
  G[t] = lo | (hi << 16);  // G word index = l*64 + k
}

// ------------------------------------------------- stage 1: truncated forward DFT
__global__ __launch_bounds__(512) void k_dft(
    const float* __restrict__ q, const float2* __restrict__ tab,
    float* __restrict__ pQr, float* __restrict__ pQi) {
  __shared__ float2 s_tab[L_];
  int tid = threadIdx.x;
#pragma unroll
  for (int i = 0; i < 8; ++i) s_tab[tid + i * 512] = tab[tid + i * 512];
  __syncthreads();

  int c = blockIdx.x, b = blockIdx.y;
  int w = tid >> 6, lane = tid & 63;
  int kb = w * 8;
  int db = lane * 8;

  float ar[8][8], ai[8][8];
#pragma unroll
  for (int kk = 0; kk < 8; ++kk)
#pragma unroll
    for (int j = 0; j < 8; ++j) { ar[kk][j] = 0.f; ai[kk][j] = 0.f; }

  int idx[8];
  int l0 = c * LCH;
#pragma unroll
  for (int kk = 0; kk < 8; ++kk) idx[kk] = ((kb + kk) * l0) & (L_ - 1);

  const float* qp = q + (((size_t)b * L_ + l0) * D_ + db);
#pragma unroll 2
  for (int l = 0; l < LCH; ++l) {
    float4 q0 = *(const float4*)qp;
    float4 q1 = *(const float4*)(qp + 4);
    qp += D_;
    float qv[8] = {q0.x, q0.y, q0.z, q0.w, q1.x, q1.y, q1.z, q1.w};
#pragma unroll
    for (int kk = 0; kk < 8; ++kk) {
      float2 t = s_tab[idx[kk]];
      idx[kk] = (idx[kk] + kb + kk) & (L_ - 1);
#pragma unroll
      for (int j = 0; j < 8; ++j) {
        ar[kk][j] += qv[j] * t.x;
        ai[kk][j] -= qv[j] * t.y;
      }
    }
  }

#pragma unroll
  for (int kk = 0; kk < 8; ++kk) {
    size_t base = (((size_t)b * NC_ + c) * M_ + (kb + kk)) * D_ + db;
    *(float4*)(pQr + base)     = make_float4(ar[kk][0], ar[kk][1], ar[kk][2], ar[kk][3]);
    *(float4*)(pQr + base + 4) = make_float4(ar[kk][4], ar[kk][5], ar[kk][6], ar[kk][7]);
    *(float4*)(pQi + base)     = make_float4(ai[kk][0], ai[kk][1], ai[kk][2], ai[kk][3]);
    *(float4*)(pQi + base + 4) = make_float4(ai[kk][4], ai[kk][5], ai[kk][6], ai[kk][7]);
  }
}

// ----------------------------------- reduce chunks + transpose to Qt[b][d][k] (float2)
__global__ void k_red(const float* __restrict__ pQr, const float* __restrict__ pQi,
                      float2* __restrict__ Qt) {
  int g = blockIdx.x * 256 + threadIdx.x;  // B_*M_*D_ threads
  int d = g & (D_ - 1);
  int k = (g >> 9) & (M_ - 1);
  int b = g >> 15;
  float ar = 0.f, ai = 0.f;
  for (int c = 0; c < NC_; ++c) {
    size_t base = (((size_t)b * NC_ + c) * M_ + k) * D_ + d;
    ar += pQr[base];
    ai += pQi[base];
  }
  Qt[((size_t)b * D_ + d) * M_ + k] = make_float2(ar, ai);
}

// ---------------------------------------------- stage 2: mode mixing (complex GEMM)
__global__ __launch_bounds__(256, 4) void k_mix(
    const float* __restrict__ wr_, const float* __restrict__ wi_,
    const float* __restrict__ Qt /* float2 as float */, float2* __restrict__ pO) {
  constexpr int DC = D_ / DCH;
  int tid = threadIdx.x;
  int w = tid >> 6, lane = tid & 63;
  int kq = lane & 15, dd = lane >> 4;
  int k0 = kq * 4;
  int e = blockIdx.x * 4 + w;
  int dc = blockIdx.y;

  float or_[B_][4], oi_[B_][4];
#pragma unroll
  for (int b = 0; b < B_; ++b)
#pragma unroll
    for (int kk = 0; kk < 4; ++kk) { or_[b][kk] = 0.f; oi_[b][kk] = 0.f; }

  int d0 = dc * DC + dd;
  const float* wrp = wr_ + ((size_t)d0 * D_ + e) * M_ + k0;
  const float* wip = wi_ + ((size_t)d0 * D_ + e) * M_ + k0;
  const float* qt0 = Qt + ((size_t)d0 * M_ + k0) * 2;

#pragma unroll 2
  for (int s = 0; s < DC; s += 4) {
    float4 wr4 = *(const float4*)wrp;
    float4 wi4 = *(const float4*)wip;
    wrp += (size_t)4 * D_ * M_;
    wip += (size_t)4 * D_ * M_;
    const float* qp = qt0;
#pragma unroll
    for (int b = 0; b < B_; ++b) {
      float4 qa = *(const float4*)qp;        // r0 i0 r1 i1
      float4 qb = *(const float4*)(qp + 4);  // r2 i2 r3 i3
      qp += (size_t)D_ * M_ * 2;
      or_[b][0] += qa.x * wr4.x - qa.y * wi4.x;
      oi_[b][0] += qa.x * wi4.x + qa.y * wr4.x;
      or_[b][1] += qa.z * wr4.y - qa.w * wi4.y;
      oi_[b][1] += qa.z * wi4.y + qa.w * wr4.y;
      or_[b][2] += qb.x * wr4.z - qb.y * wi4.z;
      oi_[b][2] += qb.x * wi4.z + qb.y * wr4.z;
      or_[b][3] += qb.z * wr4.w - qb.w * wi4.w;
      oi_[b][3] += qb.z * wi4.w + qb.w * wr4.w;
    }
    qt0 += 4 * M_ * 2;
  }

#pragma unroll
  for (int b = 0; b < B_; ++b)
#pragma unroll
    for (int kk = 0; kk < 4; ++kk) {
      or_[b][kk] += __shfl_xor(or_[b][kk], 16, 64);
      or_[b][kk] += __shfl_xor(or_[b][kk], 32, 64);
      oi_[b][kk] += __shfl_xor(oi_[b][kk], 16, 64);
      oi_[b][kk] += __shfl_xor(oi_[b][kk], 32, 64);
    }

  if (dd == 0) {
    float* base = (float*)pO;
#pragma unroll
    for (int b = 0; b < B_; ++b) {
      size_t off = ((((size_t)dc * B_ + b) * D_ + e) * M_ + k0) * 2;
      *(float4*)(base + off)     = make_float4(or_[b][0], oi_[b][0], or_[b][1], oi_[b][1]);
      *(float4*)(base + off + 4) = make_float4(or_[b][2], oi_[b][2], or_[b][3], oi_[b][3]);
    }
  }
}

// ------------------------- reduce pO chunks over dc + convert to bf16 P[b][e][128]
__global__ __launch_bounds__(256) void k_psum(const float* __restrict__ pO,
                                              unsigned* __restrict__ P) {
  int g = blockIdx.x * 256 + threadIdx.x;  // B_*D_*128/4 = 131072
  size_t base = (size_t)g * 4;
  constexpr size_t S = (size_t)B_ * D_ * M_ * 2;
  float4 s = make_float4(0.f, 0.f, 0.f, 0.f);
#pragma unroll
  for (int c = 0; c < DCH; ++c) {
    float4 v = *(const float4*)(pO + c * S + base);
    s.x += v.x; s.y += v.y; s.z += v.z; s.w += v.w;
  }
  unsigned w0 = (unsigned)f2bf(s.x) | ((unsigned)f2bf(s.y) << 16);
  unsigned w1 = (unsigned)f2bf(s.z) | ((unsigned)f2bf(s.w) << 16);
  P[g * 2]     = w0;
  P[g * 2 + 1] = w1;
}

// ------------------------- stage 3: y[b] = G(4096x128) * P[b](512x128)^T via MFMA
#define LST 72  // shorts per LDS row: 64 data + 8 pad (16B) -> 2-way reads (free)
__global__ __launch_bounds__(256, 2) void k_inv_mfma(
    const short* __restrict__ G, const short* __restrict__ P,
    float* __restrict__ y) {
  __shared__ short lds[2 * 128 * LST];  // 36,864 B
  short* As = lds;
  short* Bs = lds + 128 * LST;

  int tid = threadIdx.x;
  int lt = blockIdx.x, et = blockIdx.y, b = blockIdx.z;
  int l0 = lt * 128, e0 = et * 128;

  int wv = tid >> 6, lane = tid & 63;
  int wrow = wv >> 1, wcol = wv & 1;
  int lr = lane & 15, kg = lane >> 4;

  const short* Gb = G + (size_t)l0 * 128;
  const short* Pb = P + (size_t)b * D_ * 128 + (size_t)e0 * 128;

  f4 acc[4][4];
#pragma unroll
  for (int mi = 0; mi < 4; ++mi)
#pragma unroll
    for (int ni = 0; ni < 4; ++ni) {
      f4 z = {0.f, 0.f, 0.f, 0.f};
      acc[mi][ni] = z;
    }

#pragma unroll
  for (int kh = 0; kh < 2; ++kh) {
    if (kh) __syncthreads();
    // stage K-half: 128 rows x 64 shorts = 8 x 16B chunks per row, A and B
#pragma unroll
    for (int i = 0; i < 4; ++i) {
      int idx = i * 256 + tid;          // 0..1023
      int row = idx >> 3, c = idx & 7;
      *(uint4*)(As + row * LST + c * 8) =
          *(const uint4*)(Gb + (size_t)row * 128 + kh * 64 + c * 8);
      *(uint4*)(Bs + row * LST + c * 8) =
          *(const uint4*)(Pb + (size_t)row * 128 + kh * 64 + c * 8);
    }
    __syncthreads();

#pragma unroll
    for (int ks = 0; ks < 2; ++ks) {
      bh8 a[4], bf[4];
#pragma unroll
      for (int i = 0; i < 4; ++i) {
        a[i]  = *(const bh8*)(As + (wrow * 64 + i * 16 + lr) * LST + ks * 32 + kg * 8);
        bf[i] = *(const bh8*)(Bs + (wcol * 64 + i * 16 + lr) * LST + ks * 32 + kg * 8);
      }
#pragma unroll
      for (int mi = 0; mi < 4; ++mi)
#pragma unroll
        for (int ni = 0; ni < 4; ++ni)
          acc[mi][ni] = __builtin_amdgcn_mfma_f32_16x16x32_bf16(
              a[mi], bf[ni], acc[mi][ni], 0, 0, 0);
    }
  }

  // C/D layout: col = lane&15, row = (lane>>4)*4 + j   [verified m89]
#pragma unroll
  for (int mi = 0; mi < 4; ++mi) {
    int lg = l0 + wrow * 64 + mi * 16 + kg * 4;
#pragma unroll
    for (int ni = 0; ni < 4; ++ni) {
      int e = e0 + wcol * 64 + ni * 16 + lr;
#pragma unroll
      for (int j = 0; j < 4; ++j)
        y[((size_t)b * L_ + (lg + j)) * D_ + e] = acc[mi][ni][j];
    }
  }
}

// --------------------------------------------------------------------- launcher
extern "C" void kernel_launch(void* const* d_in, const int* in_sizes, int n_in,
                              void* d_out, int out_size, void* d_ws, size_t ws_size,
                              hipStream_t stream) {
  const float* q  = (const float*)d_in[0];
  const float* wr = (const float*)d_in[1];
  const float* wi = (const float*)d_in[2];
  float* out = (float*)d_out;
  char* ws = (char*)d_ws;

  // ws: tab 32KB | Qt 2MB | Gbf 1MB | Pbf 1MB  (~4.2 MB total; R0 proved >=10MB)
  float2* tab   = (float2*)ws;
  float2* Qt    = (float2*)(ws + (32u << 10));
  unsigned* Gbf = (unsigned*)(ws + (32u << 10) + (2u << 20));
  unsigned* Pbf = (unsigned*)(ws + (32u << 10) + (3u << 20));

  // Stage-1 partials and stage-2 pO live in d_out (dead regions, stream-ordered):
  float* pQr = out;                                  // 32 MiB
  float* pQi = out + (size_t)B_ * NC_ * M_ * D_;     // 32 MiB
  float* pO  = out;                                  // 16.8 MB (after k_red)

  hipLaunchKernelGGL(k_tab, dim3(L_ / 256), dim3(256), 0, stream, tab);
  hipLaunchKernelGGL(k_gtab, dim3((L_ * M_) / 256), dim3(256), 0, stream, Gbf);
  hipLaunchKernelGGL(k_dft, dim3(NC_, B_), dim3(512), 0, stream, q, tab, pQr, pQi);
  hipLaunchKernelGGL(k_red, dim3((B_ * M_ * D_) / 256), dim3(256), 0, stream,
                     pQr, pQi, Qt);
  hipLaunchKernelGGL(k_mix, dim3(D_ / 4, DCH), dim3(256), 0, stream,
                     wr, wi, (const float*)Qt, (float2*)pO);
  hipLaunchKernelGGL(k_psum, dim3((B_ * D_ * M_ * 2 / 4) / 256), dim3(256), 0,
                     stream, pO, Pbf);
  hipLaunchKernelGGL(k_inv_mfma, dim3(L_ / 128, D_ / 128, B_), dim3(256), 0,
                     stream, (const short*)Gbf, (const short*)Pbf, out);
}

// Round 5
// 162.147 us; speedup vs baseline: 1.7242x; 1.0932x over previous
//
#include <hip/hip_runtime.h>

#define B_ 8
#define L_ 4096
#define D_ 512
#define M_ 64
#define NC_ 32            // l-chunks for stage 1
#define LCH (L_ / NC_)    // 128

typedef __attribute__((ext_vector_type(8))) short bh8;
typedef __attribute__((ext_vector_type(4))) float f4;

__device__ inline unsigned short f2bf(float f) {
  unsigned u = __float_as_uint(f);
  return (unsigned short)((u + 0x7fffu + ((u >> 16) & 1u)) >> 16);
}
__device__ inline unsigned packbf(float lo, float hi) {
  return (unsigned)f2bf(lo) | ((unsigned)f2bf(hi) << 16);
}

// ---------------------------------------------------------------- twiddle table
__global__ void k_tab(float2* __restrict__ tab) {
  int t = blockIdx.x * blockDim.x + threadIdx.x;
  if (t < L_) {
    double ang = 6.283185307179586476925286766559 * (double)t / (double)L_;
    tab[t] = make_float2((float)cos(ang), (float)sin(ang));
  }
}

// ----------------------------------------- inverse-DFT coefficient matrix (bf16)
// Column-grouped layout to match P: G[l][j<64] = ck*cos(2pi j l/L),
// G[l][64+k] = -ck*sin(2pi k l/L). ck = 1/L (k=0) else 2/L.
__global__ void k_gtab(unsigned short* __restrict__ G) {
  int t = blockIdx.x * 256 + threadIdx.x;  // L_*128 = 524288
  int l = t >> 7, j = t & 127;
  int k = j & 63, part = j >> 6;
  int ph = (k * l) & (L_ - 1);
  double ang = 6.283185307179586476925286766559 * (double)ph / (double)L_;
  double ck = (k == 0 ? 1.0 : 2.0) / (double)L_;
  float v = part ? (float)(-ck * sin(ang)) : (float)(ck * cos(ang));
  G[t] = f2bf(v);
}

// ------------------------------------------------- stage 1: truncated forward DFT
__global__ __launch_bounds__(512) void k_dft(
    const float* __restrict__ q, const float2* __restrict__ tab,
    float* __restrict__ pQr, float* __restrict__ pQi) {
  __shared__ float2 s_tab[L_];
  int tid = threadIdx.x;
#pragma unroll
  for (int i = 0; i < 8; ++i) s_tab[tid + i * 512] = tab[tid + i * 512];
  __syncthreads();

  int c = blockIdx.x, b = blockIdx.y;
  int w = tid >> 6, lane = tid & 63;
  int kb = w * 8;
  int db = lane * 8;

  float ar[8][8], ai[8][8];
#pragma unroll
  for (int kk = 0; kk < 8; ++kk)
#pragma unroll
    for (int j = 0; j < 8; ++j) { ar[kk][j] = 0.f; ai[kk][j] = 0.f; }

  int idx[8];
  int l0 = c * LCH;
#pragma unroll
  for (int kk = 0; kk < 8; ++kk) idx[kk] = ((kb + kk) * l0) & (L_ - 1);

  const float* qp = q + (((size_t)b * L_ + l0) * D_ + db);
#pragma unroll 2
  for (int l = 0; l < LCH; ++l) {
    float4 q0 = *(const float4*)qp;
    float4 q1 = *(const float4*)(qp + 4);
    qp += D_;
    float qv[8] = {q0.x, q0.y, q0.z, q0.w, q1.x, q1.y, q1.z, q1.w};
#pragma unroll
    for (int kk = 0; kk < 8; ++kk) {
      float2 t = s_tab[idx[kk]];
      idx[kk] = (idx[kk] + kb + kk) & (L_ - 1);
#pragma unroll
      for (int j = 0; j < 8; ++j) {
        ar[kk][j] += qv[j] * t.x;
        ai[kk][j] -= qv[j] * t.y;
      }
    }
  }

#pragma unroll
  for (int kk = 0; kk < 8; ++kk) {
    size_t base = (((size_t)b * NC_ + c) * M_ + (kb + kk)) * D_ + db;
    *(float4*)(pQr + base)     = make_float4(ar[kk][0], ar[kk][1], ar[kk][2], ar[kk][3]);
    *(float4*)(pQr + base + 4) = make_float4(ar[kk][4], ar[kk][5], ar[kk][6], ar[kk][7]);
    *(float4*)(pQi + base)     = make_float4(ai[kk][0], ai[kk][1], ai[kk][2], ai[kk][3]);
    *(float4*)(pQi + base + 4) = make_float4(ai[kk][4], ai[kk][5], ai[kk][6], ai[kk][7]);
  }
}

// -------------- reduce chunks + pack bf16 Qbf[k][b][dpair]: (2d)=Qr, (2d+1)=Qi
__global__ void k_red(const float* __restrict__ pQr, const float* __restrict__ pQi,
                      unsigned* __restrict__ Qbf) {
  int g = blockIdx.x * 256 + threadIdx.x;  // B_*M_*D_ threads
  int d = g & (D_ - 1);
  int k = (g >> 9) & (M_ - 1);
  int b = g >> 15;
  float ar = 0.f, ai = 0.f;
  for (int c = 0; c < NC_; ++c) {
    size_t base = (((size_t)b * NC_ + c) * M_ + k) * D_ + d;
    ar += pQr[base];
    ai += pQi[base];
  }
  Qbf[((size_t)k * 8 + b) * 512 + d] = packbf(ar, ai);
}

// ------------------------- stage 2: mode mixing via MFMA (bf16)
// Block: (e-tile 16, k-quad). 512 thr = 8 waves = (kl 0..3) x (part 0..1).
// Per k, part: D[e][b] = sum_dpair A[e][dpair]*B[b][dpair], A from W (LDS,
// XOR-swizzled), B from Qbf (global, contiguous 16B). Output P bf16.
__global__ __launch_bounds__(512, 4) void k_mix_mfma(
    const float* __restrict__ wr_, const float* __restrict__ wi_,
    const unsigned* __restrict__ Qbf, unsigned short* __restrict__ P) {
  __shared__ unsigned Wt[8192];  // [kl4][part2][e16][word64] = 32 KB
  int tid = threadIdx.x;
  int et = blockIdx.x, kq = blockIdx.y;
  int e0 = et * 16, k0 = kq * 4;

  int w = tid >> 6, lane = tid & 63;
  int kl = w & 3, part = w >> 2;
  int k = k0 + kl;

  int se = tid & 15, sdg = tid >> 4;  // staging: e (0..15), d-group (0..31)

  f4 acc = {0.f, 0.f, 0.f, 0.f};

  const unsigned short* Qrow = (const unsigned short*)Qbf +
      (size_t)(k * 8 + (lane & 7)) * 1024 + ((lane >> 4) * 8);

  float4 cr0, cr1, ci0, ci1, nr0, nr1, ni0, ni1;
  {
    size_t d = sdg * 2;
    cr0 = *(const float4*)(wr_ + (d * 512 + e0 + se) * 64 + k0);
    cr1 = *(const float4*)(wr_ + ((d + 1) * 512 + e0 + se) * 64 + k0);
    ci0 = *(const float4*)(wi_ + (d * 512 + e0 + se) * 64 + k0);
    ci1 = *(const float4*)(wi_ + ((d + 1) * 512 + e0 + se) * 64 + k0);
  }

  for (int c = 0; c < 8; ++c) {
    if (c) __syncthreads();
    if (c < 7) {  // issue next-chunk loads early (hide under cvt+ds_write)
      size_t d = (size_t)(c + 1) * 64 + sdg * 2;
      nr0 = *(const float4*)(wr_ + (d * 512 + e0 + se) * 64 + k0);
      nr1 = *(const float4*)(wr_ + ((d + 1) * 512 + e0 + se) * 64 + k0);
      ni0 = *(const float4*)(wi_ + (d * 512 + e0 + se) * 64 + k0);
      ni1 = *(const float4*)(wi_ + ((d + 1) * 512 + e0 + se) * 64 + k0);
    }
    {
      int dl0 = sdg * 2, dl1 = dl0 + 1;
      int sw = (se & 7) << 2;
      int w0 = dl0 ^ sw, w1 = dl1 ^ sw;
      float r0[4] = {cr0.x, cr0.y, cr0.z, cr0.w};
      float r1[4] = {cr1.x, cr1.y, cr1.z, cr1.w};
      float i0[4] = {ci0.x, ci0.y, ci0.z, ci0.w};
      float i1[4] = {ci1.x, ci1.y, ci1.z, ci1.w};
#pragma unroll
      for (int q = 0; q < 4; ++q) {
        Wt[((q * 2 + 0) * 16 + se) * 64 + w0] = packbf(r0[q], -i0[q]);
        Wt[((q * 2 + 1) * 16 + se) * 64 + w0] = packbf(i0[q],  r0[q]);
        Wt[((q * 2 + 0) * 16 + se) * 64 + w1] = packbf(r1[q], -i1[q]);
        Wt[((q * 2 + 1) * 16 + se) * 64 + w1] = packbf(i1[q],  r1[q]);
      }
    }
    __syncthreads();
    {
      const unsigned* base = Wt + ((kl * 2 + part) * 16) * 64;
      int er = lane & 15;
      int sw = (er & 7) << 2;
#pragma unroll
      for (int ks = 0; ks < 4; ++ks) {
        bh8 bq = *(const bh8*)(Qrow + (size_t)c * 128 + ks * 32);
        int wd = (ks * 16 + (lane >> 4) * 4) ^ sw;
        bh8 af = *(const bh8*)(base + er * 64 + wd);
        acc = __builtin_amdgcn_mfma_f32_16x16x32_bf16(af, bq, acc, 0, 0, 0);
      }
    }
    if (c < 7) { cr0 = nr0; cr1 = nr1; ci0 = ni0; ci1 = ni1; }
  }

  // D[row=e][col=b]: col = lane&15, row = (lane>>4)*4 + j
  if ((lane & 15) < 8) {
    int b = lane & 15;
#pragma unroll
    for (int j = 0; j < 4; ++j) {
      int e = e0 + (lane >> 4) * 4 + j;
      P[((size_t)b * 512 + e) * 128 + part * 64 + k] = f2bf(acc[j]);
    }
  }
}

// ------------------------- stage 3: y[b] = G(4096x128) * P[b](512x128)^T via MFMA
#define LST 72  // shorts per LDS row: 64 data + 8 pad
__global__ __launch_bounds__(256, 2) void k_inv_mfma(
    const short* __restrict__ G, const short* __restrict__ P,
    float* __restrict__ y) {
  __shared__ short lds[2 * 128 * LST];  // 36,864 B
  short* As = lds;
  short* Bs = lds + 128 * LST;

  int tid = threadIdx.x;
  int lt = blockIdx.x, et = blockIdx.y, b = blockIdx.z;
  int l0 = lt * 128, e0 = et * 128;

  int wv = tid >> 6, lane = tid & 63;
  int wrow = wv >> 1, wcol = wv & 1;
  int lr = lane & 15, kg = lane >> 4;

  const short* Gb = G + (size_t)l0 * 128;
  const short* Pb = P + (size_t)b * D_ * 128 + (size_t)e0 * 128;

  f4 acc[4][4];
#pragma unroll
  for (int mi = 0; mi < 4; ++mi)
#pragma unroll
    for (int ni = 0; ni < 4; ++ni) {
      f4 z = {0.f, 0.f, 0.f, 0.f};
      acc[mi][ni] = z;
    }

#pragma unroll
  for (int kh = 0; kh < 2; ++kh) {
    if (kh) __syncthreads();
#pragma unroll
    for (int i = 0; i < 4; ++i) {
      int idx = i * 256 + tid;          // 0..1023
      int row = idx >> 3, c = idx & 7;
      *(uint4*)(As + row * LST + c * 8) =
          *(const uint4*)(Gb + (size_t)row * 128 + kh * 64 + c * 8);
      *(uint4*)(Bs + row * LST + c * 8) =
          *(const uint4*)(Pb + (size_t)row * 128 + kh * 64 + c * 8);
    }
    __syncthreads();

#pragma unroll
    for (int ks = 0; ks < 2; ++ks) {
      bh8 a[4], bf[4];
#pragma unroll
      for (int i = 0; i < 4; ++i) {
        a[i]  = *(const bh8*)(As + (wrow * 64 + i * 16 + lr) * LST + ks * 32 + kg * 8);
        bf[i] = *(const bh8*)(Bs + (wcol * 64 + i * 16 + lr) * LST + ks * 32 + kg * 8);
      }
#pragma unroll
      for (int mi = 0; mi < 4; ++mi)
#pragma unroll
        for (int ni = 0; ni < 4; ++ni)
          acc[mi][ni] = __builtin_amdgcn_mfma_f32_16x16x32_bf16(
              a[mi], bf[ni], acc[mi][ni], 0, 0, 0);
    }
  }

#pragma unroll
  for (int mi = 0; mi < 4; ++mi) {
    int lg = l0 + wrow * 64 + mi * 16 + kg * 4;
#pragma unroll
    for (int ni = 0; ni < 4; ++ni) {
      int e = e0 + wcol * 64 + ni * 16 + lr;
#pragma unroll
      for (int j = 0; j < 4; ++j)
        y[((size_t)b * L_ + (lg + j)) * D_ + e] = acc[mi][ni][j];
    }
  }
}

// --------------------------------------------------------------------- launcher
extern "C" void kernel_launch(void* const* d_in, const int* in_sizes, int n_in,
                              void* d_out, int out_size, void* d_ws, size_t ws_size,
                              hipStream_t stream) {
  const float* q  = (const float*)d_in[0];
  const float* wr = (const float*)d_in[1];
  const float* wi = (const float*)d_in[2];
  float* out = (float*)d_out;
  char* ws = (char*)d_ws;

  // ws: tab 32KB | Gbf 1MB | Qbf 1MB | P 1MB  (~3.03 MB; <=10MB proven in R0)
  float2* tab         = (float2*)ws;
  unsigned short* Gbf = (unsigned short*)(ws + (32u << 10));
  unsigned* Qbf       = (unsigned*)(ws + (32u << 10) + (1u << 20));
  unsigned short* P   = (unsigned short*)(ws + (32u << 10) + (2u << 20));

  // Stage-1 partials live in d_out (dead before k_inv writes it):
  float* pQr = out;
  float* pQi = out + (size_t)B_ * NC_ * M_ * D_;

  hipLaunchKernelGGL(k_tab, dim3(L_ / 256), dim3(256), 0, stream, tab);
  hipLaunchKernelGGL(k_gtab, dim3((L_ * 128) / 256), dim3(256), 0, stream, Gbf);
  hipLaunchKernelGGL(k_dft, dim3(NC_, B_), dim3(512), 0, stream, q, tab, pQr, pQi);
  hipLaunchKernelGGL(k_red, dim3((B_ * M_ * D_) / 256), dim3(256), 0, stream,
                     pQr, pQi, Qbf);
  hipLaunchKernelGGL(k_mix_mfma, dim3(D_ / 16, M_ / 4), dim3(512), 0, stream,
                     wr, wi, Qbf, P);
  hipLaunchKernelGGL(k_inv_mfma, dim3(L_ / 128, D_ / 128, B_), dim3(256), 0,
                     stream, (const short*)Gbf, (const short*)P, out);
}

// Round 6
// 153.446 us; speedup vs baseline: 1.8219x; 1.0567x over previous
//
#include <hip/hip_runtime.h>

#define B_ 8
#define L_ 4096
#define D_ 512
#define M_ 64
#define NC_ 32            // l-chunks for stage 1
#define LCH (L_ / NC_)    // 128

typedef __attribute__((ext_vector_type(8))) short bh8;
typedef __attribute__((ext_vector_type(4))) float f4;

__device__ inline unsigned short f2bf(float f) {
  unsigned u = __float_as_uint(f);
  return (unsigned short)((u + 0x7fffu + ((u >> 16) & 1u)) >> 16);
}
__device__ inline unsigned packbf(float lo, float hi) {
  return (unsigned)f2bf(lo) | ((unsigned)f2bf(hi) << 16);
}

// ---------------------------------------------------------------- twiddle table
__global__ void k_tab(float2* __restrict__ tab) {
  int t = blockIdx.x * blockDim.x + threadIdx.x;
  if (t < L_) {
    double ang = 6.283185307179586476925286766559 * (double)t / (double)L_;
    tab[t] = make_float2((float)cos(ang), (float)sin(ang));
  }
}

// ----------------------------------------- inverse-DFT coefficient matrix (bf16)
// Column-grouped: G[l][j<64] = ck*cos(2pi j l/L), G[l][64+k] = -ck*sin(2pi k l/L).
__global__ void k_gtab(unsigned short* __restrict__ G) {
  int t = blockIdx.x * 256 + threadIdx.x;  // L_*128
  int l = t >> 7, j = t & 127;
  int k = j & 63, part = j >> 6;
  int ph = (k * l) & (L_ - 1);
  double ang = 6.283185307179586476925286766559 * (double)ph / (double)L_;
  double ck = (k == 0 ? 1.0 : 2.0) / (double)L_;
  float v = part ? (float)(-ck * sin(ang)) : (float)(ck * cos(ang));
  G[t] = f2bf(v);
}

// ------------------------------------------------- stage 1: truncated forward DFT
__global__ __launch_bounds__(512) void k_dft(
    const float* __restrict__ q, const float2* __restrict__ tab,
    float* __restrict__ pQr, float* __restrict__ pQi) {
  __shared__ float2 s_tab[L_];
  int tid = threadIdx.x;
#pragma unroll
  for (int i = 0; i < 8; ++i) s_tab[tid + i * 512] = tab[tid + i * 512];
  __syncthreads();

  int c = blockIdx.x, b = blockIdx.y;
  int w = tid >> 6, lane = tid & 63;
  int kb = w * 8;
  int db = lane * 8;

  float ar[8][8], ai[8][8];
#pragma unroll
  for (int kk = 0; kk < 8; ++kk)
#pragma unroll
    for (int j = 0; j < 8; ++j) { ar[kk][j] = 0.f; ai[kk][j] = 0.f; }

  int idx[8];
  int l0 = c * LCH;
#pragma unroll
  for (int kk = 0; kk < 8; ++kk) idx[kk] = ((kb + kk) * l0) & (L_ - 1);

  const float* qp = q + (((size_t)b * L_ + l0) * D_ + db);
#pragma unroll 2
  for (int l = 0; l < LCH; ++l) {
    float4 q0 = *(const float4*)qp;
    float4 q1 = *(const float4*)(qp + 4);
    qp += D_;
    float qv[8] = {q0.x, q0.y, q0.z, q0.w, q1.x, q1.y, q1.z, q1.w};
#pragma unroll
    for (int kk = 0; kk < 8; ++kk) {
      float2 t = s_tab[idx[kk]];
      idx[kk] = (idx[kk] + kb + kk) & (L_ - 1);
#pragma unroll
      for (int j = 0; j < 8; ++j) {
        ar[kk][j] += qv[j] * t.x;
        ai[kk][j] -= qv[j] * t.y;
      }
    }
  }

#pragma unroll
  for (int kk = 0; kk < 8; ++kk) {
    size_t base = (((size_t)b * NC_ + c) * M_ + (kb + kk)) * D_ + db;
    *(float4*)(pQr + base)     = make_float4(ar[kk][0], ar[kk][1], ar[kk][2], ar[kk][3]);
    *(float4*)(pQr + base + 4) = make_float4(ar[kk][4], ar[kk][5], ar[kk][6], ar[kk][7]);
    *(float4*)(pQi + base)     = make_float4(ai[kk][0], ai[kk][1], ai[kk][2], ai[kk][3]);
    *(float4*)(pQi + base + 4) = make_float4(ai[kk][4], ai[kk][5], ai[kk][6], ai[kk][7]);
  }
}

// -------------- reduce chunks + pack bf16 Qbf[k][b][d]: word = (Qr, Qi)
__global__ void k_red(const float* __restrict__ pQr, const float* __restrict__ pQi,
                      unsigned* __restrict__ Qbf) {
  int g = blockIdx.x * 256 + threadIdx.x;  // B_*M_*D_ threads
  int d = g & (D_ - 1);
  int k = (g >> 9) & (M_ - 1);
  int b = g >> 15;
  float ar = 0.f, ai = 0.f;
  for (int c = 0; c < NC_; ++c) {
    size_t base = (((size_t)b * NC_ + c) * M_ + k) * D_ + d;
    ar += pQr[base];
    ai += pQi[base];
  }
  Qbf[((size_t)k * 8 + b) * 512 + d] = packbf(ar, ai);
}

// ------------------------- stage 2 v3: streaming mode-mix via MFMA
// grid (32 e-tiles, 8 d-chunks), 512 thr = 8 waves. Wave w owns k = w*8..w*8+8.
// Per round r (16 d's): stage W slice (contiguous 1KB/wave-instr) -> packed
// (Wr,Wi) words in LDS [k64][e16][d16 ^ swz]; 1 MFMA per k: A = W[e][2d-interleave],
// B = Q transformed per part (cols = part*8+b). fp32 partials to pOut[dc].
__global__ __launch_bounds__(512, 4) void k_mix_mfma(
    const float* __restrict__ wr_, const float* __restrict__ wi_,
    const unsigned* __restrict__ Qbf, float* __restrict__ pOut) {
  __shared__ unsigned Wt[16384];  // 64 KB
  int tid = threadIdx.x;
  int et = blockIdx.x, dc = blockIdx.y;
  int e0 = et * 16;
  int w = tid >> 6, lane = tid & 63;
  int er = lane & 15, kg = lane >> 4;
  int part = er >> 3, b = er & 7;

  f4 acc[8];
#pragma unroll
  for (int t = 0; t < 8; ++t) { f4 z = {0.f, 0.f, 0.f, 0.f}; acc[t] = z; }

  for (int r = 0; r < 4; ++r) {
    if (r) __syncthreads();
    int dbase = dc * 64 + r * 16;
    // ---- stage: 16d x 16e x 64k, fully coalesced global reads
#pragma unroll
    for (int i = 0; i < 8; ++i) {
      int f = tid + i * 512;               // 0..4095 float4 units
      int d_loc = f >> 8;
      int e = (f >> 4) & 15;
      int k4 = f & 15;
      size_t gidx = ((size_t)(dbase + d_loc) * 512 + (e0 + e)) * 16 + k4;
      float4 a  = ((const float4*)wr_)[gidx];
      float4 bb = ((const float4*)wi_)[gidx];
      int dp = d_loc ^ ((k4 & 3) << 2);
      int base = k4 * 1024 + e * 16 + dp;  // [k][e][d'] : k = k4*4+c
      Wt[base]       = packbf(a.x, bb.x);
      Wt[base + 256] = packbf(a.y, bb.y);
      Wt[base + 512] = packbf(a.z, bb.z);
      Wt[base + 768] = packbf(a.w, bb.w);
    }
    __syncthreads();
    // ---- compute: 8 k's per wave, 1 MFMA each
    int d0 = dbase + kg * 4;
#pragma unroll
    for (int t = 0; t < 8; ++t) {
      int k = w * 8 + t;
      int sw = ((k >> 2) & 3) << 2;
      union { uint4 u; bh8 h; } av, bv;
      av.u = *(const uint4*)&Wt[k * 256 + er * 16 + ((kg * 4) ^ sw)];
      uint4 qv = *(const uint4*)(Qbf + ((size_t)k * 8 + b) * 512 + d0);
      if (part == 0) {
        bv.u.x = qv.x ^ 0x80000000u; bv.u.y = qv.y ^ 0x80000000u;
        bv.u.z = qv.z ^ 0x80000000u; bv.u.w = qv.w ^ 0x80000000u;
      } else {
        bv.u.x = (qv.x >> 16) | (qv.x << 16); bv.u.y = (qv.y >> 16) | (qv.y << 16);
        bv.u.z = (qv.z >> 16) | (qv.z << 16); bv.u.w = (qv.w >> 16) | (qv.w << 16);
      }
      acc[t] = __builtin_amdgcn_mfma_f32_16x16x32_bf16(av.h, bv.h, acc[t], 0, 0, 0);
    }
  }

  // ---- epilogue: pOut[dc][k][part][b][e512], float4 over e
#pragma unroll
  for (int t = 0; t < 8; ++t) {
    int k = w * 8 + t;
    size_t off = (size_t)dc * 524288 +
                 (((size_t)k * 2 + part) * 8 + b) * 512 + e0 + kg * 4;
    *(f4*)(pOut + off) = acc[t];
  }
}

// ------------- reduce pOut over dc + transpose to bf16 P[b][e][part*64+k]
__global__ __launch_bounds__(256) void k_psum2(const float* __restrict__ pOut,
                                               unsigned* __restrict__ Pw) {
  __shared__ float sP[128 * 33];
  int tid = threadIdx.x;
  int e0 = blockIdx.x * 32, b = blockIdx.y;
  {
    int e = tid & 31, kg4 = tid >> 5;  // 8 groups of 16 cols
#pragma unroll
    for (int ii = 0; ii < 16; ++ii) {
      int col = kg4 * 16 + ii;                       // col = part*64 + k
      int rkp = ((col & 63) << 1) | (col >> 6);      // pOut row = k*2 + part
      float s = 0.f;
#pragma unroll
      for (int c = 0; c < 8; ++c)
        s += pOut[(size_t)c * 524288 + (size_t)rkp * 4096 + b * 512 + e0 + e];
      sP[col * 33 + e] = s;
    }
  }
  __syncthreads();
  {
    int e = tid >> 3, c = tid & 7;  // e 0..31, 16 cols each
    size_t wbase = (((size_t)b * 512 + e0 + e) * 128 + c * 16) >> 1;
#pragma unroll
    for (int ii = 0; ii < 8; ++ii) {
      int col = c * 16 + ii * 2;
      Pw[wbase + ii] = packbf(sP[col * 33 + e], sP[(col + 1) * 33 + e]);
    }
  }
}

// ------------------------- stage 3: y[b] = G(4096x128) * P[b](512x128)^T via MFMA
#define LST 72  // shorts per LDS row: 64 data + 8 pad
__global__ __launch_bounds__(256, 2) void k_inv_mfma(
    const short* __restrict__ G, const short* __restrict__ P,
    float* __restrict__ y) {
  __shared__ short lds[2 * 128 * LST];  // 36,864 B
  short* As = lds;
  short* Bs = lds + 128 * LST;

  int tid = threadIdx.x;
  int lt = blockIdx.x, et = blockIdx.y, b = blockIdx.z;
  int l0 = lt * 128, e0 = et * 128;

  int wv = tid >> 6, lane = tid & 63;
  int wrow = wv >> 1, wcol = wv & 1;
  int lr = lane & 15, kg = lane >> 4;

  const short* Gb = G + (size_t)l0 * 128;
  const short* Pb = P + (size_t)b * D_ * 128 + (size_t)e0 * 128;

  f4 acc[4][4];
#pragma unroll
  for (int mi = 0; mi < 4; ++mi)
#pragma unroll
    for (int ni = 0; ni < 4; ++ni) {
      f4 z = {0.f, 0.f, 0.f, 0.f};
      acc[mi][ni] = z;
    }

#pragma unroll
  for (int kh = 0; kh < 2; ++kh) {
    if (kh) __syncthreads();
#pragma unroll
    for (int i = 0; i < 4; ++i) {
      int idx = i * 256 + tid;          // 0..1023
      int row = idx >> 3, c = idx & 7;
      *(uint4*)(As + row * LST + c * 8) =
          *(const uint4*)(Gb + (size_t)row * 128 + kh * 64 + c * 8);
      *(uint4*)(Bs + row * LST + c * 8) =
          *(const uint4*)(Pb + (size_t)row * 128 + kh * 64 + c * 8);
    }
    __syncthreads();

#pragma unroll
    for (int ks = 0; ks < 2; ++ks) {
      bh8 a[4], bf[4];
#pragma unroll
      for (int i = 0; i < 4; ++i) {
        a[i]  = *(const bh8*)(As + (wrow * 64 + i * 16 + lr) * LST + ks * 32 + kg * 8);
        bf[i] = *(const bh8*)(Bs + (wcol * 64 + i * 16 + lr) * LST + ks * 32 + kg * 8);
      }
#pragma unroll
      for (int mi = 0; mi < 4; ++mi)
#pragma unroll
        for (int ni = 0; ni < 4; ++ni)
          acc[mi][ni] = __builtin_amdgcn_mfma_f32_16x16x32_bf16(
              a[mi], bf[ni], acc[mi][ni], 0, 0, 0);
    }
  }

#pragma unroll
  for (int mi = 0; mi < 4; ++mi) {
    int lg = l0 + wrow * 64 + mi * 16 + kg * 4;
#pragma unroll
    for (int ni = 0; ni < 4; ++ni) {
      int e = e0 + wcol * 64 + ni * 16 + lr;
#pragma unroll
      for (int j = 0; j < 4; ++j)
        y[((size_t)b * L_ + (lg + j)) * D_ + e] = acc[mi][ni][j];
    }
  }
}

// --------------------------------------------------------------------- launcher
extern "C" void kernel_launch(void* const* d_in, const int* in_sizes, int n_in,
                              void* d_out, int out_size, void* d_ws, size_t ws_size,
                              hipStream_t stream) {
  const float* q  = (const float*)d_in[0];
  const float* wr = (const float*)d_in[1];
  const float* wi = (const float*)d_in[2];
  float* out = (float*)d_out;
  char* ws = (char*)d_ws;

  // ws: tab 32KB | Gbf 1MB | Qbf 1MB | P 1MB  (~3.03 MB; <=10MB proven in R0)
  float2* tab         = (float2*)ws;
  unsigned short* Gbf = (unsigned short*)(ws + (32u << 10));
  unsigned* Qbf       = (unsigned*)(ws + (32u << 10) + (1u << 20));
  unsigned* Pw        = (unsigned*)(ws + (32u << 10) + (2u << 20));

  // d_out scratch phases (stream-ordered):
  //   k_dft -> pQr/pQi (67 MB), consumed by k_red;
  //   k_mix -> pOut (16.8 MB), consumed by k_psum2; k_inv overwrites all.
  float* pQr  = out;
  float* pQi  = out + (size_t)B_ * NC_ * M_ * D_;
  float* pOut = out;

  hipLaunchKernelGGL(k_tab, dim3(L_ / 256), dim3(256), 0, stream, tab);
  hipLaunchKernelGGL(k_gtab, dim3((L_ * 128) / 256), dim3(256), 0, stream, Gbf);
  hipLaunchKernelGGL(k_dft, dim3(NC_, B_), dim3(512), 0, stream, q, tab, pQr, pQi);
  hipLaunchKernelGGL(k_red, dim3((B_ * M_ * D_) / 256), dim3(256), 0, stream,
                     pQr, pQi, Qbf);
  hipLaunchKernelGGL(k_mix_mfma, dim3(D_ / 16, 8), dim3(512), 0, stream,
                     wr, wi, Qbf, pOut);
  hipLaunchKernelGGL(k_psum2, dim3(16, 8), dim3(256), 0, stream, pOut, Pw);
  hipLaunchKernelGGL(k_inv_mfma, dim3(L_ / 128, D_ / 128, B_), dim3(256), 0,
                     stream, (const short*)Gbf, (const short*)Pw, out);
}

// Round 8
// 107.711 us; speedup vs baseline: 2.5955x; 1.4246x over previous
//
#include <hip/hip_runtime.h>

#define B_ 8
#define L_ 4096
#define D_ 512
#define M_ 64

typedef __attribute__((ext_vector_type(8))) short bh8;
typedef __attribute__((ext_vector_type(4))) float f4;
typedef __attribute__((ext_vector_type(4))) unsigned u32x4;

__device__ inline unsigned short f2bf(float f) {
  unsigned u = __float_as_uint(f);
  return (unsigned short)((u + 0x7fffu + ((u >> 16) & 1u)) >> 16);
}
__device__ inline unsigned packbf(float lo, float hi) {
  return (unsigned)f2bf(lo) | ((unsigned)f2bf(hi) << 16);
}

// ---------------- forward-DFT coefficient matrix (bf16), PLAIN row-major [r][l]
// Row r = part*64 + k: part0 = cos(2pi k l/L), part1 = -sin(2pi k l/L).
__global__ void k_ftab(unsigned short* __restrict__ F) {
  int t = blockIdx.x * 256 + threadIdx.x;  // 128*4096 = 524288
  int r = t >> 12, l = t & 4095;
  int k = r & 63, part = r >> 6;
  int ph = (k * l) & (L_ - 1);
  double ang = 6.283185307179586476925286766559 * (double)ph / (double)L_;
  float v = part ? (float)(-sin(ang)) : (float)(cos(ang));
  F[t] = f2bf(v);
}

// ----------------------------------------- inverse-DFT coefficient matrix (bf16)
// Column-grouped: G[l][j<64] = ck*cos(2pi j l/L), G[l][64+k] = -ck*sin(2pi k l/L).
__global__ void k_gtab(unsigned short* __restrict__ G) {
  int t = blockIdx.x * 256 + threadIdx.x;  // L_*128
  int l = t >> 7, j = t & 127;
  int k = j & 63, part = j >> 6;
  int ph = (k * l) & (L_ - 1);
  double ang = 6.283185307179586476925286766559 * (double)ph / (double)L_;
  double ck = (k == 0 ? 1.0 : 2.0) / (double)L_;
  float v = part ? (float)(-ck * sin(ang)) : (float)(ck * cos(ang));
  G[t] = f2bf(v);
}

// ------------------------- stage 1: Qft = F(128x4096) * q[b](4096x512) via MFMA
// grid (8 d-tiles, 8 b, 8 kc), 512 thr = 8 waves (mh = w&3 row-group, nc = w>>2
// d-group). No LDS: B-frags built from line-dense scalar q loads (lane = d,
// 8 consecutive l at stride D); A-frags = contiguous b128 from L2-resident F.
__global__ __launch_bounds__(512, 4) void k_dft_mfma(
    const float* __restrict__ q, const unsigned short* __restrict__ F,
    float* __restrict__ pQ) {
  int tid = threadIdx.x;
  int dt = blockIdx.x, b = blockIdx.y, kc = blockIdx.z;
  int d0 = dt * 64;
  int lbase = kc * 512;

  int w = tid >> 6, lane = tid & 63;
  int mh = w & 3, nc = w >> 2;
  int lr = lane & 15, kg = lane >> 4;

  f4 acc[2][2];
#pragma unroll
  for (int i = 0; i < 2; ++i)
#pragma unroll
    for (int j = 0; j < 2; ++j) { f4 z = {0.f, 0.f, 0.f, 0.f}; acc[i][j] = z; }

  const unsigned short* A0 = F + (size_t)(mh * 32 + lr) * 4096 + lbase + kg * 8;
  const unsigned short* A1 = A0 + (size_t)16 * 4096;
  const float* q0 = q + ((size_t)b * L_ + lbase + kg * 8) * D_ + d0 + nc * 32 + lr;

#pragma unroll 2
  for (int s = 0; s < 16; ++s) {
    const float* qs = q0 + (size_t)s * 32 * D_;
    float v0[8], v1[8];
#pragma unroll
    for (int j = 0; j < 8; ++j) {
      v0[j] = qs[(size_t)j * D_];
      v1[j] = qs[(size_t)j * D_ + 16];
    }
    union { u32x4 u; bh8 h; } bf0, bf1;
    bf0.u.x = packbf(v0[0], v0[1]); bf0.u.y = packbf(v0[2], v0[3]);
    bf0.u.z = packbf(v0[4], v0[5]); bf0.u.w = packbf(v0[6], v0[7]);
    bf1.u.x = packbf(v1[0], v1[1]); bf1.u.y = packbf(v1[2], v1[3]);
    bf1.u.z = packbf(v1[4], v1[5]); bf1.u.w = packbf(v1[6], v1[7]);
    bh8 af0 = *(const bh8*)(A0 + s * 32);
    bh8 af1 = *(const bh8*)(A1 + s * 32);
    acc[0][0] = __builtin_amdgcn_mfma_f32_16x16x32_bf16(af0, bf0.h, acc[0][0], 0, 0, 0);
    acc[0][1] = __builtin_amdgcn_mfma_f32_16x16x32_bf16(af0, bf1.h, acc[0][1], 0, 0, 0);
    acc[1][0] = __builtin_amdgcn_mfma_f32_16x16x32_bf16(af1, bf0.h, acc[1][0], 0, 0, 0);
    acc[1][1] = __builtin_amdgcn_mfma_f32_16x16x32_bf16(af1, bf1.h, acc[1][1], 0, 0, 0);
  }

  // fp32 partials: pQ[kc][r 128][b 8][d 512]; C-layout col=lane&15, row=kg*4+j
#pragma unroll
  for (int mi = 0; mi < 2; ++mi) {
    int r = mh * 32 + mi * 16 + kg * 4;
#pragma unroll
    for (int ni = 0; ni < 2; ++ni) {
      int d = d0 + nc * 32 + ni * 16 + lr;
#pragma unroll
      for (int j = 0; j < 4; ++j)
        pQ[(((size_t)kc * 128 + (r + j)) * 8 + b) * 512 + d] = acc[mi][ni][j];
    }
  }
}

// -------------- reduce kc chunks + pack bf16 Qbf[k][b][d]: word = (Qr, Qi)
__global__ __launch_bounds__(256) void k_red2(const float* __restrict__ pQ,
                                              unsigned* __restrict__ Qbf) {
  int g = blockIdx.x * 256 + threadIdx.x;  // 64*8*128 = 65536
  int dq = g & 127;
  int b = (g >> 7) & 7;
  int k = g >> 10;
  f4 sr = {0.f, 0.f, 0.f, 0.f}, si = {0.f, 0.f, 0.f, 0.f};
#pragma unroll
  for (int kc = 0; kc < 8; ++kc) {
    size_t base = (((size_t)kc * 128 + k) * 8 + b) * 512 + dq * 4;
    sr += *(const f4*)(pQ + base);
    si += *(const f4*)(pQ + base + (size_t)64 * 8 * 512);
  }
  u32x4 o;
  o.x = packbf(sr[0], si[0]); o.y = packbf(sr[1], si[1]);
  o.z = packbf(sr[2], si[2]); o.w = packbf(sr[3], si[3]);
  *(u32x4*)(Qbf + ((size_t)k * 8 + b) * 512 + dq * 4) = o;
}

// ------------------------- stage 2: streaming mode-mix via MFMA
__global__ __launch_bounds__(512, 4) void k_mix_mfma(
    const float* __restrict__ wr_, const float* __restrict__ wi_,
    const unsigned* __restrict__ Qbf, float* __restrict__ pOut) {
  __shared__ unsigned Wt[16384];  // 64 KB
  int tid = threadIdx.x;
  int et = blockIdx.x, dc = blockIdx.y;
  int e0 = et * 16;
  int w = tid >> 6, lane = tid & 63;
  int er = lane & 15, kg = lane >> 4;
  int part = er >> 3, b = er & 7;

  f4 acc[8];
#pragma unroll
  for (int t = 0; t < 8; ++t) { f4 z = {0.f, 0.f, 0.f, 0.f}; acc[t] = z; }

  for (int r = 0; r < 4; ++r) {
    if (r) __syncthreads();
    int dbase = dc * 64 + r * 16;
#pragma unroll
    for (int i = 0; i < 8; ++i) {
      int f = tid + i * 512;               // 0..4095 float4 units
      int d_loc = f >> 8;
      int e = (f >> 4) & 15;
      int k4 = f & 15;
      size_t gidx = ((size_t)(dbase + d_loc) * 512 + (e0 + e)) * 16 + k4;
      float4 a  = ((const float4*)wr_)[gidx];
      float4 bb = ((const float4*)wi_)[gidx];
      int dp = d_loc ^ ((k4 & 3) << 2);
      int base = k4 * 1024 + e * 16 + dp;
      Wt[base]       = packbf(a.x, bb.x);
      Wt[base + 256] = packbf(a.y, bb.y);
      Wt[base + 512] = packbf(a.z, bb.z);
      Wt[base + 768] = packbf(a.w, bb.w);
    }
    __syncthreads();
    int d0 = dbase + kg * 4;
#pragma unroll
    for (int t = 0; t < 8; ++t) {
      int k = w * 8 + t;
      int sw = ((k >> 2) & 3) << 2;
      union { u32x4 u; bh8 h; } av, bv;
      av.u = *(const u32x4*)&Wt[k * 256 + er * 16 + ((kg * 4) ^ sw)];
      u32x4 qv = *(const u32x4*)(Qbf + ((size_t)k * 8 + b) * 512 + d0);
      if (part == 0) {
        bv.u.x = qv.x ^ 0x80000000u; bv.u.y = qv.y ^ 0x80000000u;
        bv.u.z = qv.z ^ 0x80000000u; bv.u.w = qv.w ^ 0x80000000u;
      } else {
        bv.u.x = (qv.x >> 16) | (qv.x << 16); bv.u.y = (qv.y >> 16) | (qv.y << 16);
        bv.u.z = (qv.z >> 16) | (qv.z << 16); bv.u.w = (qv.w >> 16) | (qv.w << 16);
      }
      acc[t] = __builtin_amdgcn_mfma_f32_16x16x32_bf16(av.h, bv.h, acc[t], 0, 0, 0);
    }
  }

#pragma unroll
  for (int t = 0; t < 8; ++t) {
    int k = w * 8 + t;
    size_t off = (size_t)dc * 524288 +
                 (((size_t)k * 2 + part) * 8 + b) * 512 + e0 + kg * 4;
    *(f4*)(pOut + off) = acc[t];
  }
}

// ------------- reduce pOut over dc + transpose to bf16 P[b][e][part*64+k]
__global__ __launch_bounds__(256) void k_psum2(const float* __restrict__ pOut,
                                               unsigned* __restrict__ Pw) {
  __shared__ float sP[128 * 33];
  int tid = threadIdx.x;
  int e0 = blockIdx.x * 32, b = blockIdx.y;
  {
    int e = tid & 31, kg4 = tid >> 5;
#pragma unroll
    for (int ii = 0; ii < 16; ++ii) {
      int col = kg4 * 16 + ii;
      int rkp = ((col & 63) << 1) | (col >> 6);
      float s = 0.f;
#pragma unroll
      for (int c = 0; c < 8; ++c)
        s += pOut[(size_t)c * 524288 + (size_t)rkp * 4096 + b * 512 + e0 + e];
      sP[col * 33 + e] = s;
    }
  }
  __syncthreads();
  {
    int e = tid >> 3, c = tid & 7;
    size_t wbase = (((size_t)b * 512 + e0 + e) * 128 + c * 16) >> 1;
#pragma unroll
    for (int ii = 0; ii < 8; ++ii) {
      int col = c * 16 + ii * 2;
      Pw[wbase + ii] = packbf(sP[col * 33 + e], sP[(col + 1) * 33 + e]);
    }
  }
}

// ------------------------- stage 3: y[b] = G(4096x128) * P[b](512x128)^T via MFMA
#define LST 72
__global__ __launch_bounds__(256, 2) void k_inv_mfma(
    const short* __restrict__ G, const short* __restrict__ P,
    float* __restrict__ y) {
  __shared__ short lds[2 * 128 * LST];
  short* As = lds;
  short* Bs = lds + 128 * LST;

  int tid = threadIdx.x;
  int lt = blockIdx.x, et = blockIdx.y, b = blockIdx.z;
  int l0 = lt * 128, e0 = et * 128;

  int wv = tid >> 6, lane = tid & 63;
  int wrow = wv >> 1, wcol = wv & 1;
  int lr = lane & 15, kg = lane >> 4;

  const short* Gb = G + (size_t)l0 * 128;
  const short* Pb = P + (size_t)b * D_ * 128 + (size_t)e0 * 128;

  f4 acc[4][4];
#pragma unroll
  for (int mi = 0; mi < 4; ++mi)
#pragma unroll
    for (int ni = 0; ni < 4; ++ni) {
      f4 z = {0.f, 0.f, 0.f, 0.f};
      acc[mi][ni] = z;
    }

#pragma unroll
  for (int kh = 0; kh < 2; ++kh) {
    if (kh) __syncthreads();
#pragma unroll
    for (int i = 0; i < 4; ++i) {
      int idx = i * 256 + tid;
      int row = idx >> 3, c = idx & 7;
      *(uint4*)(As + row * LST + c * 8) =
          *(const uint4*)(Gb + (size_t)row * 128 + kh * 64 + c * 8);
      *(uint4*)(Bs + row * LST + c * 8) =
          *(const uint4*)(Pb + (size_t)row * 128 + kh * 64 + c * 8);
    }
    __syncthreads();

#pragma unroll
    for (int ks = 0; ks < 2; ++ks) {
      bh8 a[4], bf[4];
#pragma unroll
      for (int i = 0; i < 4; ++i) {
        a[i]  = *(const bh8*)(As + (wrow * 64 + i * 16 + lr) * LST + ks * 32 + kg * 8);
        bf[i] = *(const bh8*)(Bs + (wcol * 64 + i * 16 + lr) * LST + ks * 32 + kg * 8);
      }
#pragma unroll
      for (int mi = 0; mi < 4; ++mi)
#pragma unroll
        for (int ni = 0; ni < 4; ++ni)
          acc[mi][ni] = __builtin_amdgcn_mfma_f32_16x16x32_bf16(
              a[mi], bf[ni], acc[mi][ni], 0, 0, 0);
    }
  }

#pragma unroll
  for (int mi = 0; mi < 4; ++mi) {
    int lg = l0 + wrow * 64 + mi * 16 + kg * 4;
#pragma unroll
    for (int ni = 0; ni < 4; ++ni) {
      int e = e0 + wcol * 64 + ni * 16 + lr;
#pragma unroll
      for (int j = 0; j < 4; ++j)
        y[((size_t)b * L_ + (lg + j)) * D_ + e] = acc[mi][ni][j];
    }
  }
}

// --------------------------------------------------------------------- launcher
extern "C" void kernel_launch(void* const* d_in, const int* in_sizes, int n_in,
                              void* d_out, int out_size, void* d_ws, size_t ws_size,
                              hipStream_t stream) {
  const float* q  = (const float*)d_in[0];
  const float* wr = (const float*)d_in[1];
  const float* wi = (const float*)d_in[2];
  float* out = (float*)d_out;
  char* ws = (char*)d_ws;

  // ws: Fbf 1MB | Gbf 1MB | Qbf 1MB | Pw 1MB = 4 MB (<=10MB proven)
  unsigned short* Fbf = (unsigned short*)ws;
  unsigned short* Gbf = (unsigned short*)(ws + (1u << 20));
  unsigned* Qbf       = (unsigned*)(ws + (2u << 20));
  unsigned* Pw        = (unsigned*)(ws + (3u << 20));

  // d_out scratch phases (stream-ordered):
  //   k_dft_mfma -> pQ (16.8 MB), consumed by k_red2;
  //   k_mix_mfma -> pOut (16.8 MB, same bytes), consumed by k_psum2;
  //   k_inv_mfma overwrites all 64 MB.
  float* pQ   = out;
  float* pOut = out;

  hipLaunchKernelGGL(k_ftab, dim3((128 * L_) / 256), dim3(256), 0, stream, Fbf);
  hipLaunchKernelGGL(k_gtab, dim3((L_ * 128) / 256), dim3(256), 0, stream, Gbf);
  hipLaunchKernelGGL(k_dft_mfma, dim3(8, 8, 8), dim3(512), 0, stream,
                     q, Fbf, pQ);
  hipLaunchKernelGGL(k_red2, dim3(65536 / 256), dim3(256), 0, stream, pQ, Qbf);
  hipLaunchKernelGGL(k_mix_mfma, dim3(D_ / 16, 8), dim3(512), 0, stream,
                     wr, wi, Qbf, pOut);
  hipLaunchKernelGGL(k_psum2, dim3(16, 8), dim3(256), 0, stream, pOut, Pw);
  hipLaunchKernelGGL(k_inv_mfma, dim3(L_ / 128, D_ / 128, B_), dim3(256), 0,
                     stream, (const short*)Gbf, (const short*)Pw, out);
}